// Round 1
// baseline (243.713 us; speedup 1.0000x reference)
//
#include <hip/hip_runtime.h>
#include <math.h>

#define NPLANES 24   // B*C = 8*3
#define BLK 256

__device__ __forceinline__ int refl(int v, int S) {
    if (v < 0) v = -v;
    if (v >= S) v = 2 * S - 2 - v;
    return v;
}

// pyrdown: out(i,j) = sum_{a,b in 0..5} w[a]w[b]/1024 * in[refl(2i-2+a)][refl(2j-2+b)]
// (reflect-pad + 5x5 binomial + 2x2 avg pool collapsed to one 6-tap separable stencil)
// If dout != null, also writes d = |in - nearest_up(out)| for the 2x2 pixels covered.
__global__ void pyrdown_kernel(const float* __restrict__ in, float* __restrict__ out,
                               float* __restrict__ dout, int Si) {
    const int So = Si >> 1;
    const int total = NPLANES * So * So;
    int idx = blockIdx.x * BLK + threadIdx.x;
    if (idx >= total) return;
    int j = idx % So;
    int rest = idx / So;
    int i = rest % So;
    int p = rest / So;
    const float* ip = in + (size_t)p * Si * Si;
    const float w[6] = {1.f, 5.f, 10.f, 10.f, 5.f, 1.f};
    int rx[6], ry[6];
#pragma unroll
    for (int a = 0; a < 6; ++a) {
        ry[a] = refl(2 * i - 2 + a, Si);
        rx[a] = refl(2 * j - 2 + a, Si);
    }
    float acc = 0.f;
#pragma unroll
    for (int a = 0; a < 6; ++a) {
        const float* rp = ip + (size_t)ry[a] * Si;
        float r = 0.f;
#pragma unroll
        for (int b = 0; b < 6; ++b) r += w[b] * rp[rx[b]];
        acc += w[a] * r;
    }
    acc *= (1.f / 1024.f);
    out[(size_t)p * So * So + (size_t)i * So + j] = acc;
    if (dout != nullptr) {
        float* dp = dout + (size_t)p * Si * Si;
#pragma unroll
        for (int di = 0; di < 2; ++di)
#pragma unroll
            for (int dj = 0; dj < 2; ++dj) {
                int y = 2 * i + di, x = 2 * j + dj;
                dp[(size_t)y * Si + x] = fabsf(ip[(size_t)y * Si + x] - acc);
            }
    }
}

// One block per (level, plane): plane min/max + mean of 16x16 tile maxima
// (torch loop range(0, S-16, 16) -> nt = S/16 - 1 tiles per axis; 0 for S<=16).
// Emits A = (1-lm)^2/(mx-mn), B = -mn*A so sm_norm(d) = A*d + B.
__global__ void stats_kernel(const float* __restrict__ dBase, float* __restrict__ Aout,
                             float* __restrict__ Bout) {
    int li = blockIdx.x / NPLANES;
    int p = blockIdx.x % NPLANES;
    int S = 256 >> li;
    int n = S * S;
    int dOff = 2097152 - (2097152 >> (2 * li));
    const float* d = dBase + dOff + (size_t)p * n;
    int tid = threadIdx.x;
    __shared__ float s0[BLK], s1[BLK];
    float mn = 3.402823466e38f, mx = -3.402823466e38f;
    for (int k = tid; k < n; k += BLK) {
        float v = d[k];
        mn = fminf(mn, v);
        mx = fmaxf(mx, v);
    }
    s0[tid] = mn; s1[tid] = mx;
    __syncthreads();
    for (int s = BLK / 2; s > 0; s >>= 1) {
        if (tid < s) {
            s0[tid] = fminf(s0[tid], s0[tid + s]);
            s1[tid] = fmaxf(s1[tid], s1[tid + s]);
        }
        __syncthreads();
    }
    mn = s0[0]; mx = s1[0];
    __syncthreads();
    int nt = (S >= 32) ? ((S >> 4) - 1) : 0;
    int ntiles = nt * nt;
    float tsum = 0.f;
    for (int t = tid; t < ntiles; t += BLK) {
        int ty = t / nt, tx = t % nt;
        float tm = -3.402823466e38f;
        const float* base = d + (size_t)(ty * 16) * S + tx * 16;
        for (int yy = 0; yy < 16; ++yy)
            for (int xx = 0; xx < 16; ++xx)
                tm = fmaxf(tm, base[yy * S + xx]);
        tsum += tm;
    }
    s0[tid] = tsum;
    __syncthreads();
    for (int s = BLK / 2; s > 0; s >>= 1) {
        if (tid < s) s0[tid] += s0[tid + s];
        __syncthreads();
    }
    if (tid == 0) {
        float inv = 1.f / (mx - mn);
        float lm = (ntiles > 0) ? (s0[0] / (float)ntiles - mn) * inv : 0.f;
        float g = 1.f - lm;
        g = g * g;
        Aout[blockIdx.x] = g * inv;
        Bout[blockIdx.x] = -mn * g * inv;
    }
}

// out[b,y,x] = (1/3) * sum_c sum_li (A*bilin(d_li, y, x) + B)
__global__ void final_kernel(const float* __restrict__ dBase, const float* __restrict__ A,
                             const float* __restrict__ Bc, float* __restrict__ out) {
    __shared__ float sA[168], sB[168];
    int tid = threadIdx.x;
    if (tid < 168) { sA[tid] = A[tid]; sB[tid] = Bc[tid]; }
    __syncthreads();
    int idx = blockIdx.x * BLK + tid;
    int x = idx & 511;
    int y = (idx >> 9) & 511;
    int b = idx >> 18;
    float acc = 0.f;
#pragma unroll
    for (int li = 0; li < 7; ++li) {
        const int S = 256 >> li;
        const int dOff = 2097152 - (2097152 >> (2 * li));
        const float scale = (float)S * (1.0f / 512.0f);
        float fy = (y + 0.5f) * scale - 0.5f;
        float fx = (x + 0.5f) * scale - 0.5f;
        int y0 = (int)floorf(fy);
        int x0 = (int)floorf(fx);
        float wy = fy - (float)y0;
        float wx = fx - (float)x0;
        int y0c = min(max(y0, 0), S - 1), y1c = min(max(y0 + 1, 0), S - 1);
        int x0c = min(max(x0, 0), S - 1), x1c = min(max(x0 + 1, 0), S - 1);
        float w00 = (1.f - wy) * (1.f - wx), w01 = (1.f - wy) * wx;
        float w10 = wy * (1.f - wx), w11 = wy * wx;
        const float* dl = dBase + dOff;
#pragma unroll
        for (int c = 0; c < 3; ++c) {
            int p = b * 3 + c;
            const float* dp = dl + (size_t)p * S * S;
            float v = w00 * dp[y0c * S + x0c] + w01 * dp[y0c * S + x1c] +
                      w10 * dp[y1c * S + x0c] + w11 * dp[y1c * S + x1c];
            acc += sA[li * NPLANES + p] * v + sB[li * NPLANES + p];
        }
    }
    out[idx] = acc * (1.0f / 3.0f);
}

extern "C" void kernel_launch(void* const* d_in, const int* in_sizes, int n_in,
                              void* d_out, int out_size, void* d_ws, size_t ws_size,
                              hipStream_t stream) {
    (void)in_sizes; (void)n_in; (void)out_size; (void)ws_size;
    const float* x = (const float*)d_in[0];
    float* ws = (float*)d_ws;
    float* out = (float*)d_out;

    // Workspace layout (floats):
    // pyr[1..8] then d[0..6] then A[168], B[168]
    static const size_t po[9] = {0, 0, 1572864, 1966080, 2064384,
                                 2088960, 2095104, 2096640, 2097024};
    float* pyr[9];
    for (int L = 1; L <= 8; ++L) pyr[L] = ws + po[L];
    float* dBase = ws + 2097120;
    float* A = dBase + 2097024;
    float* Bc = A + 168;

    // Level 1 from raw x (initial _norm_pc is a scale/shift no-op for the output)
    {
        const int Si = 512, So = 256;
        int total = NPLANES * So * So;
        pyrdown_kernel<<<(total + BLK - 1) / BLK, BLK, 0, stream>>>(x, pyr[1], nullptr, Si);
    }
    for (int L = 2; L <= 8; ++L) {
        int Si = 512 >> (L - 1), So = Si >> 1;
        int total = NPLANES * So * So;
        int dOff = 2097152 - (2097152 >> (2 * (L - 2)));
        pyrdown_kernel<<<(total + BLK - 1) / BLK, BLK, 0, stream>>>(
            pyr[L - 1], pyr[L], dBase + dOff, Si);
    }
    stats_kernel<<<7 * NPLANES, BLK, 0, stream>>>(dBase, A, Bc);
    final_kernel<<<(8 * 512 * 512) / BLK, BLK, 0, stream>>>(dBase, A, Bc, out);
}

// Round 2
// 181.649 us; speedup vs baseline: 1.3417x; 1.3417x over previous
//
#include <hip/hip_runtime.h>
#include <math.h>

#define NPLANES 24   // B*C = 8*3
#define BLK 256
#define FINF 3.402823466e38f

__host__ __device__ __forceinline__ int d_off(int li) {
    // cumulative float offset of d-level li inside dBase (sizes 256^2..4^2 x24)
    return 2097152 - (2097152 >> (2 * li));
}

__device__ __forceinline__ int refl(int v, int S) {
    if (v < 0) v = -v;
    if (v >= S) v = 2 * S - 2 - v;
    return v;
}

// Block-wide reductions over 256 threads; all threads must call.
__device__ __forceinline__ float bredMin(float v, float* red, int tid) {
    red[tid] = v; __syncthreads();
    for (int s = 128; s > 0; s >>= 1) {
        if (tid < s) red[tid] = fminf(red[tid], red[tid + s]);
        __syncthreads();
    }
    float r = red[0]; __syncthreads(); return r;
}
__device__ __forceinline__ float bredMax(float v, float* red, int tid) {
    red[tid] = v; __syncthreads();
    for (int s = 128; s > 0; s >>= 1) {
        if (tid < s) red[tid] = fmaxf(red[tid], red[tid + s]);
        __syncthreads();
    }
    float r = red[0]; __syncthreads(); return r;
}
__device__ __forceinline__ float bredSum(float v, float* red, int tid) {
    red[tid] = v; __syncthreads();
    for (int s = 128; s > 0; s >>= 1) {
        if (tid < s) red[tid] += red[tid + s];
        __syncthreads();
    }
    float r = red[0]; __syncthreads(); return r;
}

// 6-tap separable collapsed pyrdown stencil on an LDS plane of size SxS.
__device__ __forceinline__ float stencil6(const float* s, int S, int i, int j) {
    const float w[6] = {1.f, 5.f, 10.f, 10.f, 5.f, 1.f};
    int rx[6];
#pragma unroll
    for (int b = 0; b < 6; ++b) rx[b] = refl(2 * j - 2 + b, S);
    float acc = 0.f;
#pragma unroll
    for (int a = 0; a < 6; ++a) {
        int ry = refl(2 * i - 2 + a, S);
        const float* rp = s + ry * S;
        float r = 0.f;
#pragma unroll
        for (int b = 0; b < 6; ++b) r += w[b] * rp[rx[b]];
        acc += w[a] * r;
    }
    return acc * (1.f / 1024.f);
}

// Global-memory pyrdown (reflect pad + 5x5 binomial + bilinear half == 6-tap stride 2).
// If dout != null also writes d = |in - nearest_up(out)| for the 2x2 covered pixels.
__global__ void pyrdown_kernel(const float* __restrict__ in, float* __restrict__ out,
                               float* __restrict__ dout, int Si) {
    const int So = Si >> 1;
    const int total = NPLANES * So * So;
    int idx = blockIdx.x * BLK + threadIdx.x;
    if (idx >= total) return;
    int j = idx % So;
    int rest = idx / So;
    int i = rest % So;
    int p = rest / So;
    const float* ip = in + (size_t)p * Si * Si;
    const float w[6] = {1.f, 5.f, 10.f, 10.f, 5.f, 1.f};
    int rx[6], ry[6];
#pragma unroll
    for (int a = 0; a < 6; ++a) {
        ry[a] = refl(2 * i - 2 + a, Si);
        rx[a] = refl(2 * j - 2 + a, Si);
    }
    float acc = 0.f;
#pragma unroll
    for (int a = 0; a < 6; ++a) {
        const float* rp = ip + (size_t)ry[a] * Si;
        float r = 0.f;
#pragma unroll
        for (int b = 0; b < 6; ++b) r += w[b] * rp[rx[b]];
        acc += w[a] * r;
    }
    acc *= (1.f / 1024.f);
    out[(size_t)p * So * So + (size_t)i * So + j] = acc;
    if (dout != nullptr) {
        float* dp = dout + (size_t)p * Si * Si;
#pragma unroll
        for (int di = 0; di < 2; ++di)
#pragma unroll
            for (int dj = 0; dj < 2; ++dj) {
                int y = 2 * i + di, x = 2 * j + dj;
                dp[(size_t)y * Si + x] = fabsf(ip[(size_t)y * Si + x] - acc);
            }
    }
}

// One block per plane: pyr4..pyr8 + d2..d6 entirely in LDS, plus stats (A,B)
// for levels li=2..6. Removes 4 tiny launches + 120 serial stats blocks.
__global__ __launch_bounds__(256) void fused_small_kernel(const float* __restrict__ pyr3,
                                                          float* __restrict__ dBase,
                                                          float* __restrict__ A,
                                                          float* __restrict__ B) {
    __shared__ float sp3[4096], sd2[4096];
    __shared__ float sp4[1024], sd3[1024];
    __shared__ float sp5[256], sd4[256];
    __shared__ float sp6[64], sd5[64];
    __shared__ float sp7[16], sd6[16];
    __shared__ float red[256];
    __shared__ float tmaxLds[16];
    const int tid = threadIdx.x;
    const int p = blockIdx.x;
    const float* g3 = pyr3 + (size_t)p * 4096;
    for (int k = tid; k < 4096; k += 256) sp3[k] = g3[k];
    __syncthreads();

    // pyr4 (32x32) + d2 (64x64)
    float* d2g = dBase + d_off(2) + (size_t)p * 4096;
    for (int k = tid; k < 1024; k += 256) {
        int i = k >> 5, j = k & 31;
        float v = stencil6(sp3, 64, i, j);
        sp4[k] = v;
#pragma unroll
        for (int di = 0; di < 2; ++di)
#pragma unroll
            for (int dj = 0; dj < 2; ++dj) {
                int y = 2 * i + di, x = 2 * j + dj;
                float dv = fabsf(sp3[y * 64 + x] - v);
                sd2[y * 64 + x] = dv;
                d2g[y * 64 + x] = dv;
            }
    }
    __syncthreads();

    // pyr5 (16x16) + d3 (32x32)
    {
        int i = tid >> 4, j = tid & 15;
        float v = stencil6(sp4, 32, i, j);
        sp5[tid] = v;
        float* d3g = dBase + d_off(3) + (size_t)p * 1024;
#pragma unroll
        for (int di = 0; di < 2; ++di)
#pragma unroll
            for (int dj = 0; dj < 2; ++dj) {
                int y = 2 * i + di, x = 2 * j + dj;
                float dv = fabsf(sp4[y * 32 + x] - v);
                sd3[y * 32 + x] = dv;
                d3g[y * 32 + x] = dv;
            }
    }
    __syncthreads();

    // pyr6 (8x8) + d4 (16x16)
    if (tid < 64) {
        int i = tid >> 3, j = tid & 7;
        float v = stencil6(sp5, 16, i, j);
        sp6[tid] = v;
        float* d4g = dBase + d_off(4) + (size_t)p * 256;
#pragma unroll
        for (int di = 0; di < 2; ++di)
#pragma unroll
            for (int dj = 0; dj < 2; ++dj) {
                int y = 2 * i + di, x = 2 * j + dj;
                float dv = fabsf(sp5[y * 16 + x] - v);
                sd4[y * 16 + x] = dv;
                d4g[y * 16 + x] = dv;
            }
    }
    __syncthreads();

    // pyr7 (4x4) + d5 (8x8)
    if (tid < 16) {
        int i = tid >> 2, j = tid & 3;
        float v = stencil6(sp6, 8, i, j);
        sp7[tid] = v;
        float* d5g = dBase + d_off(5) + (size_t)p * 64;
#pragma unroll
        for (int di = 0; di < 2; ++di)
#pragma unroll
            for (int dj = 0; dj < 2; ++dj) {
                int y = 2 * i + di, x = 2 * j + dj;
                float dv = fabsf(sp6[y * 8 + x] - v);
                sd5[y * 8 + x] = dv;
                d5g[y * 8 + x] = dv;
            }
    }
    __syncthreads();

    // pyr8 (2x2) + d6 (4x4)
    if (tid < 4) {
        int i = tid >> 1, j = tid & 1;
        float v = stencil6(sp7, 4, i, j);
        float* d6g = dBase + d_off(6) + (size_t)p * 16;
#pragma unroll
        for (int di = 0; di < 2; ++di)
#pragma unroll
            for (int dj = 0; dj < 2; ++dj) {
                int y = 2 * i + di, x = 2 * j + dj;
                float dv = fabsf(sp7[y * 4 + x] - v);
                sd6[y * 4 + x] = dv;
                d6g[y * 4 + x] = dv;
            }
    }
    __syncthreads();

    // ---- stats li=2 (S=64, nt=3, ntiles=9) ----
    {
        float mn = FINF, mx = -FINF;
        for (int k = tid; k < 4096; k += 256) {
            float v = sd2[k];
            mn = fminf(mn, v); mx = fmaxf(mx, v);
        }
        mn = bredMin(mn, red, tid);
        mx = bredMax(mx, red, tid);
        // per-(tile,row) strip maxima: tile = tid>>4, row = tid&15
        {
            int t = tid >> 4, r = tid & 15;
            int ty = t >> 2, tx = t & 3;
            const float* rowp = sd2 + (ty * 16 + r) * 64 + tx * 16;
            float sm = -FINF;
#pragma unroll
            for (int c = 0; c < 16; ++c) sm = fmaxf(sm, rowp[c]);
            red[tid] = sm;
        }
        __syncthreads();
        if (tid < 16) {
            float tm = -FINF;
            for (int r = 0; r < 16; ++r) tm = fmaxf(tm, red[tid * 16 + r]);
            tmaxLds[tid] = tm;
        }
        __syncthreads();
        if (tid == 0) {
            float s = 0.f;
            for (int ty = 0; ty < 3; ++ty)
                for (int tx = 0; tx < 3; ++tx) s += tmaxLds[ty * 4 + tx];
            float inv = 1.f / (mx - mn);
            float lm = (s * (1.f / 9.f) - mn) * inv;
            float g = (1.f - lm) * (1.f - lm);
            A[2 * NPLANES + p] = g * inv;
            B[2 * NPLANES + p] = -mn * g * inv;
        }
        __syncthreads();
    }
    // ---- stats li=3 (S=32, ntiles=1) ----
    {
        float mn = FINF, mx = -FINF;
        for (int k = tid; k < 1024; k += 256) {
            float v = sd3[k];
            mn = fminf(mn, v); mx = fmaxf(mx, v);
        }
        mn = bredMin(mn, red, tid);
        mx = bredMax(mx, red, tid);
        float e = sd3[(tid >> 4) * 32 + (tid & 15)];   // the single interior 16x16 tile
        float tm = bredMax(e, red, tid);
        if (tid == 0) {
            float inv = 1.f / (mx - mn);
            float lm = (tm - mn) * inv;
            float g = (1.f - lm) * (1.f - lm);
            A[3 * NPLANES + p] = g * inv;
            B[3 * NPLANES + p] = -mn * g * inv;
        }
    }
    // ---- stats li=4,5,6 (ntiles=0 -> lm=0) ----
    {
        float v = sd4[tid];
        float mn = bredMin(v, red, tid);
        float mx = bredMax(v, red, tid);
        if (tid == 0) {
            float inv = 1.f / (mx - mn);
            A[4 * NPLANES + p] = inv; B[4 * NPLANES + p] = -mn * inv;
        }
    }
    {
        float v = (tid < 64) ? sd5[tid] : FINF;
        float mn = bredMin(v, red, tid);
        v = (tid < 64) ? sd5[tid] : -FINF;
        float mx = bredMax(v, red, tid);
        if (tid == 0) {
            float inv = 1.f / (mx - mn);
            A[5 * NPLANES + p] = inv; B[5 * NPLANES + p] = -mn * inv;
        }
    }
    {
        float v = (tid < 16) ? sd6[tid] : FINF;
        float mn = bredMin(v, red, tid);
        v = (tid < 16) ? sd6[tid] : -FINF;
        float mx = bredMax(v, red, tid);
        if (tid == 0) {
            float inv = 1.f / (mx - mn);
            A[6 * NPLANES + p] = inv; B[6 * NPLANES + p] = -mn * inv;
        }
    }
}

// One block per 16x16 tile of d0/d1; writes tile min/max.
__global__ __launch_bounds__(256) void tile_kernel(const float* __restrict__ dBase,
                                                   float* __restrict__ tileMin,
                                                   float* __restrict__ tileMax) {
    __shared__ float red[256];
    int t = blockIdx.x;
    int tid = threadIdx.x;
    int li, S, plane, tile, ty, tx;
    if (t < 6144) { li = 0; S = 256; plane = t >> 8; tile = t & 255; ty = tile >> 4; tx = tile & 15; }
    else { t -= 6144; li = 1; S = 128; plane = t >> 6; tile = t & 63; ty = tile >> 3; tx = tile & 7; }
    const float* d = dBase + d_off(li) + (size_t)plane * S * S;
    int row = ty * 16 + (tid >> 4), col = tx * 16 + (tid & 15);
    float v = d[row * S + col];
    float mn = bredMin(v, red, tid);
    float mx = bredMax(v, red, tid);
    if (tid == 0) {
        tileMin[blockIdx.x] = mn;
        tileMax[blockIdx.x] = mx;
    }
}

// One block per (li in {0,1}, plane): fold tile stats -> A,B.
__global__ __launch_bounds__(256) void reduce_kernel(const float* __restrict__ tileMin,
                                                     const float* __restrict__ tileMax,
                                                     float* __restrict__ A,
                                                     float* __restrict__ B) {
    __shared__ float red[256];
    int li = blockIdx.x / NPLANES;
    int p = blockIdx.x % NPLANES;
    int tid = threadIdx.x;
    int TP = (li == 0) ? 256 : 64;     // tiles per plane
    int TA = (li == 0) ? 16 : 8;       // tiles per axis
    int nt = TA - 1;                   // interior tiles per axis
    int base = (li == 0) ? p * 256 : 6144 + p * 64;
    float tmn = (tid < TP) ? tileMin[base + tid] : FINF;
    float tmx = (tid < TP) ? tileMax[base + tid] : -FINF;
    float mn = bredMin(tmn, red, tid);
    float mx = bredMax(tmx, red, tid);
    int ty = (li == 0) ? (tid >> 4) : (tid >> 3);
    int tx = (li == 0) ? (tid & 15) : (tid & 7);
    float s = (tid < TP && ty < nt && tx < nt) ? tmx : 0.f;
    float sum = bredSum(s, red, tid);
    if (tid == 0) {
        float ntiles = (float)(nt * nt);
        float inv = 1.f / (mx - mn);
        float lm = (sum / ntiles - mn) * inv;
        float g = (1.f - lm) * (1.f - lm);
        A[li * NPLANES + p] = g * inv;
        B[li * NPLANES + p] = -mn * g * inv;
    }
}

// out[b,y,x] = (1/3) * sum_c sum_li (A*bilin(d_li, y, x) + B)
__global__ void final_kernel(const float* __restrict__ dBase, const float* __restrict__ A,
                             const float* __restrict__ Bc, float* __restrict__ out) {
    __shared__ float sA[168], sB[168];
    int tid = threadIdx.x;
    if (tid < 168) { sA[tid] = A[tid]; sB[tid] = Bc[tid]; }
    __syncthreads();
    int idx = blockIdx.x * BLK + tid;
    int x = idx & 511;
    int y = (idx >> 9) & 511;
    int b = idx >> 18;
    float acc = 0.f;
#pragma unroll
    for (int li = 0; li < 7; ++li) {
        const int S = 256 >> li;
        const int dOff = d_off(li);
        const float scale = (float)S * (1.0f / 512.0f);
        float fy = (y + 0.5f) * scale - 0.5f;
        float fx = (x + 0.5f) * scale - 0.5f;
        int y0 = (int)floorf(fy);
        int x0 = (int)floorf(fx);
        float wy = fy - (float)y0;
        float wx = fx - (float)x0;
        int y0c = min(max(y0, 0), S - 1), y1c = min(max(y0 + 1, 0), S - 1);
        int x0c = min(max(x0, 0), S - 1), x1c = min(max(x0 + 1, 0), S - 1);
        float w00 = (1.f - wy) * (1.f - wx), w01 = (1.f - wy) * wx;
        float w10 = wy * (1.f - wx), w11 = wy * wx;
        const float* dl = dBase + dOff;
#pragma unroll
        for (int c = 0; c < 3; ++c) {
            int p = b * 3 + c;
            const float* dp = dl + (size_t)p * S * S;
            float v = w00 * dp[y0c * S + x0c] + w01 * dp[y0c * S + x1c] +
                      w10 * dp[y1c * S + x0c] + w11 * dp[y1c * S + x1c];
            acc += sA[li * NPLANES + p] * v + sB[li * NPLANES + p];
        }
    }
    out[idx] = acc * (1.0f / 3.0f);
}

extern "C" void kernel_launch(void* const* d_in, const int* in_sizes, int n_in,
                              void* d_out, int out_size, void* d_ws, size_t ws_size,
                              hipStream_t stream) {
    (void)in_sizes; (void)n_in; (void)out_size; (void)ws_size;
    const float* x = (const float*)d_in[0];
    float* ws = (float*)d_ws;
    float* out = (float*)d_out;

    // Workspace layout (float offsets):
    float* pyr1 = ws;                  // 256^2*24 = 1572864
    float* pyr2 = ws + 1572864;        // 128^2*24 =  393216
    float* pyr3 = ws + 1966080;        //  64^2*24 =   98304
    float* dBase = ws + 2064384;       // d0..d6   = 2097024
    float* tileMin = ws + 4161408;     // 7680
    float* tileMax = ws + 4169088;     // 7680
    float* A = ws + 4176768;           // 168
    float* Bc = ws + 4176936;          // 168

    // Level 1 from raw x (initial _norm_pc is an affine no-op for the output)
    pyrdown_kernel<<<(NPLANES * 256 * 256 + BLK - 1) / BLK, BLK, 0, stream>>>(x, pyr1, nullptr, 512);
    pyrdown_kernel<<<(NPLANES * 128 * 128 + BLK - 1) / BLK, BLK, 0, stream>>>(pyr1, pyr2, dBase + d_off(0), 256);
    pyrdown_kernel<<<(NPLANES * 64 * 64 + BLK - 1) / BLK, BLK, 0, stream>>>(pyr2, pyr3, dBase + d_off(1), 128);
    fused_small_kernel<<<NPLANES, 256, 0, stream>>>(pyr3, dBase, A, Bc);
    tile_kernel<<<7680, 256, 0, stream>>>(dBase, tileMin, tileMax);
    reduce_kernel<<<2 * NPLANES, 256, 0, stream>>>(tileMin, tileMax, A, Bc);
    final_kernel<<<(8 * 512 * 512) / BLK, BLK, 0, stream>>>(dBase, A, Bc, out);
}

// Round 3
// 146.842 us; speedup vs baseline: 1.6597x; 1.2370x over previous
//
#include <hip/hip_runtime.h>
#include <math.h>

#define NPLANES 24   // B*C = 8*3
#define BLK 256
#define FINF 3.402823466e38f

__host__ __device__ __forceinline__ int d_off(int li) {
    // cumulative float offset of d-level li inside dBase (sizes 256^2..4^2 x24)
    return 2097152 - (2097152 >> (2 * li));
}

__device__ __forceinline__ int refl(int v, int S) {
    if (v < 0) v = -v;
    if (v >= S) v = 2 * S - 2 - v;
    return v;
}

// Block-wide reductions over 256 threads; all threads must call.
__device__ __forceinline__ float bredMin(float v, float* red, int tid) {
    red[tid] = v; __syncthreads();
    for (int s = 128; s > 0; s >>= 1) {
        if (tid < s) red[tid] = fminf(red[tid], red[tid + s]);
        __syncthreads();
    }
    float r = red[0]; __syncthreads(); return r;
}
__device__ __forceinline__ float bredMax(float v, float* red, int tid) {
    red[tid] = v; __syncthreads();
    for (int s = 128; s > 0; s >>= 1) {
        if (tid < s) red[tid] = fmaxf(red[tid], red[tid + s]);
        __syncthreads();
    }
    float r = red[0]; __syncthreads(); return r;
}
__device__ __forceinline__ float bredSum(float v, float* red, int tid) {
    red[tid] = v; __syncthreads();
    for (int s = 128; s > 0; s >>= 1) {
        if (tid < s) red[tid] += red[tid + s];
        __syncthreads();
    }
    float r = red[0]; __syncthreads(); return r;
}

// 6-tap separable collapsed pyrdown stencil on an LDS plane of size SxS.
__device__ __forceinline__ float stencil6(const float* s, int S, int i, int j) {
    const float w[6] = {1.f, 5.f, 10.f, 10.f, 5.f, 1.f};
    int rx[6];
#pragma unroll
    for (int b = 0; b < 6; ++b) rx[b] = refl(2 * j - 2 + b, S);
    float acc = 0.f;
#pragma unroll
    for (int a = 0; a < 6; ++a) {
        int ry = refl(2 * i - 2 + a, S);
        const float* rp = s + ry * S;
        float r = 0.f;
#pragma unroll
        for (int b = 0; b < 6; ++b) r += w[b] * rp[rx[b]];
        acc += w[a] * r;
    }
    return acc * (1.f / 1024.f);
}

// Global-memory pyrdown (reflect pad + 5x5 binomial + bilinear half == 6-tap stride 2).
// If dout != null also writes d = |in - nearest_up(out)| for the 2x2 covered pixels.
__global__ void pyrdown_kernel(const float* __restrict__ in, float* __restrict__ out,
                               float* __restrict__ dout, int Si) {
    const int So = Si >> 1;
    const int total = NPLANES * So * So;
    int idx = blockIdx.x * BLK + threadIdx.x;
    if (idx >= total) return;
    int j = idx % So;
    int rest = idx / So;
    int i = rest % So;
    int p = rest / So;
    const float* ip = in + (size_t)p * Si * Si;
    const float w[6] = {1.f, 5.f, 10.f, 10.f, 5.f, 1.f};
    int rx[6], ry[6];
#pragma unroll
    for (int a = 0; a < 6; ++a) {
        ry[a] = refl(2 * i - 2 + a, Si);
        rx[a] = refl(2 * j - 2 + a, Si);
    }
    float acc = 0.f;
#pragma unroll
    for (int a = 0; a < 6; ++a) {
        const float* rp = ip + (size_t)ry[a] * Si;
        float r = 0.f;
#pragma unroll
        for (int b = 0; b < 6; ++b) r += w[b] * rp[rx[b]];
        acc += w[a] * r;
    }
    acc *= (1.f / 1024.f);
    out[(size_t)p * So * So + (size_t)i * So + j] = acc;
    if (dout != nullptr) {
        float* dp = dout + (size_t)p * Si * Si;
#pragma unroll
        for (int di = 0; di < 2; ++di)
#pragma unroll
            for (int dj = 0; dj < 2; ++dj) {
                int y = 2 * i + di, x = 2 * j + dj;
                dp[(size_t)y * Si + x] = fabsf(ip[(size_t)y * Si + x] - acc);
            }
    }
}

// One block per plane: pyr4..pyr8 + d2..d6 entirely in LDS, plus stats (A,B)
// for levels li=2..6.
__global__ __launch_bounds__(256) void fused_small_kernel(const float* __restrict__ pyr3,
                                                          float* __restrict__ dBase,
                                                          float* __restrict__ A,
                                                          float* __restrict__ B) {
    __shared__ float sp3[4096], sd2[4096];
    __shared__ float sp4[1024], sd3[1024];
    __shared__ float sp5[256], sd4[256];
    __shared__ float sp6[64], sd5[64];
    __shared__ float sp7[16], sd6[16];
    __shared__ float red[256];
    __shared__ float tmaxLds[16];
    const int tid = threadIdx.x;
    const int p = blockIdx.x;
    const float* g3 = pyr3 + (size_t)p * 4096;
    for (int k = tid; k < 4096; k += 256) sp3[k] = g3[k];
    __syncthreads();

    // pyr4 (32x32) + d2 (64x64)
    float* d2g = dBase + d_off(2) + (size_t)p * 4096;
    for (int k = tid; k < 1024; k += 256) {
        int i = k >> 5, j = k & 31;
        float v = stencil6(sp3, 64, i, j);
        sp4[k] = v;
#pragma unroll
        for (int di = 0; di < 2; ++di)
#pragma unroll
            for (int dj = 0; dj < 2; ++dj) {
                int y = 2 * i + di, x = 2 * j + dj;
                float dv = fabsf(sp3[y * 64 + x] - v);
                sd2[y * 64 + x] = dv;
                d2g[y * 64 + x] = dv;
            }
    }
    __syncthreads();

    // pyr5 (16x16) + d3 (32x32)
    {
        int i = tid >> 4, j = tid & 15;
        float v = stencil6(sp4, 32, i, j);
        sp5[tid] = v;
        float* d3g = dBase + d_off(3) + (size_t)p * 1024;
#pragma unroll
        for (int di = 0; di < 2; ++di)
#pragma unroll
            for (int dj = 0; dj < 2; ++dj) {
                int y = 2 * i + di, x = 2 * j + dj;
                float dv = fabsf(sp4[y * 32 + x] - v);
                sd3[y * 32 + x] = dv;
                d3g[y * 32 + x] = dv;
            }
    }
    __syncthreads();

    // pyr6 (8x8) + d4 (16x16)
    if (tid < 64) {
        int i = tid >> 3, j = tid & 7;
        float v = stencil6(sp5, 16, i, j);
        sp6[tid] = v;
        float* d4g = dBase + d_off(4) + (size_t)p * 256;
#pragma unroll
        for (int di = 0; di < 2; ++di)
#pragma unroll
            for (int dj = 0; dj < 2; ++dj) {
                int y = 2 * i + di, x = 2 * j + dj;
                float dv = fabsf(sp5[y * 16 + x] - v);
                sd4[y * 16 + x] = dv;
                d4g[y * 16 + x] = dv;
            }
    }
    __syncthreads();

    // pyr7 (4x4) + d5 (8x8)
    if (tid < 16) {
        int i = tid >> 2, j = tid & 3;
        float v = stencil6(sp6, 8, i, j);
        sp7[tid] = v;
        float* d5g = dBase + d_off(5) + (size_t)p * 64;
#pragma unroll
        for (int di = 0; di < 2; ++di)
#pragma unroll
            for (int dj = 0; dj < 2; ++dj) {
                int y = 2 * i + di, x = 2 * j + dj;
                float dv = fabsf(sp6[y * 8 + x] - v);
                sd5[y * 8 + x] = dv;
                d5g[y * 8 + x] = dv;
            }
    }
    __syncthreads();

    // pyr8 (2x2) + d6 (4x4)
    if (tid < 4) {
        int i = tid >> 1, j = tid & 1;
        float v = stencil6(sp7, 4, i, j);
        float* d6g = dBase + d_off(6) + (size_t)p * 16;
#pragma unroll
        for (int di = 0; di < 2; ++di)
#pragma unroll
            for (int dj = 0; dj < 2; ++dj) {
                int y = 2 * i + di, x = 2 * j + dj;
                float dv = fabsf(sp7[y * 4 + x] - v);
                sd6[y * 4 + x] = dv;
                d6g[y * 4 + x] = dv;
            }
    }
    __syncthreads();

    // ---- stats li=2 (S=64, nt=3, ntiles=9) ----
    {
        float mn = FINF, mx = -FINF;
        for (int k = tid; k < 4096; k += 256) {
            float v = sd2[k];
            mn = fminf(mn, v); mx = fmaxf(mx, v);
        }
        mn = bredMin(mn, red, tid);
        mx = bredMax(mx, red, tid);
        {
            int t = tid >> 4, r = tid & 15;
            int ty = t >> 2, tx = t & 3;
            const float* rowp = sd2 + (ty * 16 + r) * 64 + tx * 16;
            float sm = -FINF;
#pragma unroll
            for (int c = 0; c < 16; ++c) sm = fmaxf(sm, rowp[c]);
            red[tid] = sm;
        }
        __syncthreads();
        if (tid < 16) {
            float tm = -FINF;
            for (int r = 0; r < 16; ++r) tm = fmaxf(tm, red[tid * 16 + r]);
            tmaxLds[tid] = tm;
        }
        __syncthreads();
        if (tid == 0) {
            float s = 0.f;
            for (int ty = 0; ty < 3; ++ty)
                for (int tx = 0; tx < 3; ++tx) s += tmaxLds[ty * 4 + tx];
            float inv = 1.f / (mx - mn);
            float lm = (s * (1.f / 9.f) - mn) * inv;
            float g = (1.f - lm) * (1.f - lm);
            A[2 * NPLANES + p] = g * inv;
            B[2 * NPLANES + p] = -mn * g * inv;
        }
        __syncthreads();
    }
    // ---- stats li=3 (S=32, ntiles=1) ----
    {
        float mn = FINF, mx = -FINF;
        for (int k = tid; k < 1024; k += 256) {
            float v = sd3[k];
            mn = fminf(mn, v); mx = fmaxf(mx, v);
        }
        mn = bredMin(mn, red, tid);
        mx = bredMax(mx, red, tid);
        float e = sd3[(tid >> 4) * 32 + (tid & 15)];   // the single interior 16x16 tile
        float tm = bredMax(e, red, tid);
        if (tid == 0) {
            float inv = 1.f / (mx - mn);
            float lm = (tm - mn) * inv;
            float g = (1.f - lm) * (1.f - lm);
            A[3 * NPLANES + p] = g * inv;
            B[3 * NPLANES + p] = -mn * g * inv;
        }
    }
    // ---- stats li=4,5,6 (ntiles=0 -> lm=0) ----
    {
        float v = sd4[tid];
        float mn = bredMin(v, red, tid);
        float mx = bredMax(v, red, tid);
        if (tid == 0) {
            float inv = 1.f / (mx - mn);
            A[4 * NPLANES + p] = inv; B[4 * NPLANES + p] = -mn * inv;
        }
    }
    {
        float v = (tid < 64) ? sd5[tid] : FINF;
        float mn = bredMin(v, red, tid);
        v = (tid < 64) ? sd5[tid] : -FINF;
        float mx = bredMax(v, red, tid);
        if (tid == 0) {
            float inv = 1.f / (mx - mn);
            A[5 * NPLANES + p] = inv; B[5 * NPLANES + p] = -mn * inv;
        }
    }
    {
        float v = (tid < 16) ? sd6[tid] : FINF;
        float mn = bredMin(v, red, tid);
        v = (tid < 16) ? sd6[tid] : -FINF;
        float mx = bredMax(v, red, tid);
        if (tid == 0) {
            float inv = 1.f / (mx - mn);
            A[6 * NPLANES + p] = inv; B[6 * NPLANES + p] = -mn * inv;
        }
    }
}

// One block per 16x16 tile of d0/d1; writes tile min/max.
__global__ __launch_bounds__(256) void tile_kernel(const float* __restrict__ dBase,
                                                   float* __restrict__ tileMin,
                                                   float* __restrict__ tileMax) {
    __shared__ float red[256];
    int t = blockIdx.x;
    int tid = threadIdx.x;
    int li, S, plane, tile, ty, tx;
    if (t < 6144) { li = 0; S = 256; plane = t >> 8; tile = t & 255; ty = tile >> 4; tx = tile & 15; }
    else { t -= 6144; li = 1; S = 128; plane = t >> 6; tile = t & 63; ty = tile >> 3; tx = tile & 7; }
    const float* d = dBase + d_off(li) + (size_t)plane * S * S;
    int row = ty * 16 + (tid >> 4), col = tx * 16 + (tid & 15);
    float v = d[row * S + col];
    float mn = bredMin(v, red, tid);
    float mx = bredMax(v, red, tid);
    if (tid == 0) {
        tileMin[blockIdx.x] = mn;
        tileMax[blockIdx.x] = mx;
    }
}

// One block per (li in {0,1}, plane): fold tile stats -> A,B.
__global__ __launch_bounds__(256) void reduce_kernel(const float* __restrict__ tileMin,
                                                     const float* __restrict__ tileMax,
                                                     float* __restrict__ A,
                                                     float* __restrict__ B) {
    __shared__ float red[256];
    int li = blockIdx.x / NPLANES;
    int p = blockIdx.x % NPLANES;
    int tid = threadIdx.x;
    int TP = (li == 0) ? 256 : 64;     // tiles per plane
    int TA = (li == 0) ? 16 : 8;       // tiles per axis
    int nt = TA - 1;                   // interior tiles per axis
    int base = (li == 0) ? p * 256 : 6144 + p * 64;
    float tmn = (tid < TP) ? tileMin[base + tid] : FINF;
    float tmx = (tid < TP) ? tileMax[base + tid] : -FINF;
    float mn = bredMin(tmn, red, tid);
    float mx = bredMax(tmx, red, tid);
    int ty = (li == 0) ? (tid >> 4) : (tid >> 3);
    int tx = (li == 0) ? (tid & 15) : (tid & 7);
    float s = (tid < TP && ty < nt && tx < nt) ? tmx : 0.f;
    float sum = bredSum(s, red, tid);
    if (tid == 0) {
        float ntiles = (float)(nt * nt);
        float inv = 1.f / (mx - mn);
        float lm = (sum / ntiles - mn) * inv;
        float g = (1.f - lm) * (1.f - lm);
        A[li * NPLANES + p] = g * inv;
        B[li * NPLANES + p] = -mn * g * inv;
    }
}

// Tiled final gather: block = 64x64 output tile of one image b.
// Channel-combined (A pre-multiplied) level patches staged in LDS, then
// each thread bilinearly interpolates a 4x4 register sub-block from LDS.
// Exact: bilinear is linear, so sum_c A_c*bilin(d_c)+B_c = bilin(sum A*d) + sum B.
__global__ __launch_bounds__(256) void final_kernel(const float* __restrict__ dBase,
                                                    const float* __restrict__ A,
                                                    const float* __restrict__ Bc,
                                                    float* __restrict__ out) {
    __shared__ float patch[1650];
    __shared__ float sBtot;
    const int tid = threadIdx.x;
    const int b = blockIdx.x >> 6;
    const int tile = blockIdx.x & 63;
    const int yb = (tile >> 3) << 6;
    const int xb = (tile & 7) << 6;

    if (tid == 0) {
        float s = 0.f;
        for (int k = 0; k < 7; ++k)
            for (int c = 0; c < 3; ++c) s += Bc[k * NPLANES + b * 3 + c];
        sBtot = s;
    }

    const int dims[7] = {34, 18, 10, 6, 4, 3, 3};
    const int lofs[7] = {0, 1156, 1480, 1580, 1616, 1632, 1641};
    int baseY[7], baseX[7];
#pragma unroll
    for (int li = 0; li < 7; ++li) {
        const int S = 256 >> li;
        const float s = 1.f / (float)(2 << li);
        baseY[li] = (int)floorf((yb + 0.5f) * s - 0.5f);
        baseX[li] = (int)floorf((xb + 0.5f) * s - 0.5f);
        const int dim = dims[li];
        const int n = dim * dim;
        const float* d0p = dBase + d_off(li) + (size_t)(b * 3) * S * S;
        const float* d1p = d0p + S * S;
        const float* d2p = d1p + S * S;
        const float A0 = A[li * NPLANES + b * 3 + 0];
        const float A1 = A[li * NPLANES + b * 3 + 1];
        const float A2 = A[li * NPLANES + b * 3 + 2];
        for (int k = tid; k < n; k += 256) {
            int r = k / dim, c = k - r * dim;
            int sr = min(max(baseY[li] + r, 0), S - 1);
            int sc = min(max(baseX[li] + c, 0), S - 1);
            int si = sr * S + sc;
            patch[lofs[li] + k] = A0 * d0p[si] + A1 * d1p[si] + A2 * d2p[si];
        }
    }
    __syncthreads();

    const int ty = tid >> 4, tx = tid & 15;
    const int gy0 = yb + (ty << 2), gx0 = xb + (tx << 2);
    float acc[4][4];
#pragma unroll
    for (int i = 0; i < 4; ++i)
#pragma unroll
        for (int j = 0; j < 4; ++j) acc[i][j] = 0.f;

#pragma unroll
    for (int li = 0; li < 7; ++li) {
        const int dim = dims[li];
        const float* P = patch + lofs[li];
        const float s = 1.f / (float)(2 << li);
        int pr[4], pc[4];
        float wy[4], wx[4];
#pragma unroll
        for (int k = 0; k < 4; ++k) {
            float fy = (gy0 + k + 0.5f) * s - 0.5f;
            float fl = floorf(fy);
            wy[k] = fy - fl;
            pr[k] = (int)fl - baseY[li];
            float fx = (gx0 + k + 0.5f) * s - 0.5f;
            fl = floorf(fx);
            wx[k] = fx - fl;
            pc[k] = (int)fl - baseX[li];
        }
#pragma unroll
        for (int i = 0; i < 4; ++i) {
            const float* r0 = P + pr[i] * dim;
            const float* r1 = r0 + dim;
#pragma unroll
            for (int j = 0; j < 4; ++j) {
                float a0 = r0[pc[j]], a1 = r0[pc[j] + 1];
                float b0 = r1[pc[j]], b1 = r1[pc[j] + 1];
                float h0 = a0 + wx[j] * (a1 - a0);
                float h1 = b0 + wx[j] * (b1 - b0);
                acc[i][j] += h0 + wy[i] * (h1 - h0);
            }
        }
    }

    const float bt = sBtot;
    float* op = out + ((size_t)b * 512 + gy0) * 512 + gx0;
#pragma unroll
    for (int i = 0; i < 4; ++i) {
        float4 v;
        v.x = (acc[i][0] + bt) * (1.f / 3.f);
        v.y = (acc[i][1] + bt) * (1.f / 3.f);
        v.z = (acc[i][2] + bt) * (1.f / 3.f);
        v.w = (acc[i][3] + bt) * (1.f / 3.f);
        *(float4*)(op + (size_t)i * 512) = v;
    }
}

extern "C" void kernel_launch(void* const* d_in, const int* in_sizes, int n_in,
                              void* d_out, int out_size, void* d_ws, size_t ws_size,
                              hipStream_t stream) {
    (void)in_sizes; (void)n_in; (void)out_size; (void)ws_size;
    const float* x = (const float*)d_in[0];
    float* ws = (float*)d_ws;
    float* out = (float*)d_out;

    // Workspace layout (float offsets):
    float* pyr1 = ws;                  // 256^2*24 = 1572864
    float* pyr2 = ws + 1572864;        // 128^2*24 =  393216
    float* pyr3 = ws + 1966080;        //  64^2*24 =   98304
    float* dBase = ws + 2064384;       // d0..d6   = 2097024
    float* tileMin = ws + 4161408;     // 7680
    float* tileMax = ws + 4169088;     // 7680
    float* A = ws + 4176768;           // 168
    float* Bc = ws + 4176936;          // 168

    // Level 1 from raw x (initial _norm_pc is an affine no-op for the output)
    pyrdown_kernel<<<(NPLANES * 256 * 256 + BLK - 1) / BLK, BLK, 0, stream>>>(x, pyr1, nullptr, 512);
    pyrdown_kernel<<<(NPLANES * 128 * 128 + BLK - 1) / BLK, BLK, 0, stream>>>(pyr1, pyr2, dBase + d_off(0), 256);
    pyrdown_kernel<<<(NPLANES * 64 * 64 + BLK - 1) / BLK, BLK, 0, stream>>>(pyr2, pyr3, dBase + d_off(1), 128);
    fused_small_kernel<<<NPLANES, 256, 0, stream>>>(pyr3, dBase, A, Bc);
    tile_kernel<<<7680, 256, 0, stream>>>(dBase, tileMin, tileMax);
    reduce_kernel<<<2 * NPLANES, 256, 0, stream>>>(tileMin, tileMax, A, Bc);
    final_kernel<<<8 * 64, 256, 0, stream>>>(dBase, A, Bc, out);
}

// Round 4
// 126.319 us; speedup vs baseline: 1.9293x; 1.1625x over previous
//
#include <hip/hip_runtime.h>
#include <math.h>

#define NPLANES 24   // B*C = 8*3
#define BLK 256
#define FINF 3.402823466e38f

__host__ __device__ __forceinline__ int d_off(int li) {
    // cumulative float offset of d-level li inside dBase (sizes 256^2..4^2 x24)
    return 2097152 - (2097152 >> (2 * li));
}

__device__ __forceinline__ int refl(int v, int S) {
    if (v < 0) v = -v;
    if (v >= S) v = 2 * S - 2 - v;
    return v;
}

// Block-wide reductions over 256 threads; all threads must call.
__device__ __forceinline__ float bredMin(float v, float* red, int tid) {
    red[tid] = v; __syncthreads();
    for (int s = 128; s > 0; s >>= 1) {
        if (tid < s) red[tid] = fminf(red[tid], red[tid + s]);
        __syncthreads();
    }
    float r = red[0]; __syncthreads(); return r;
}
__device__ __forceinline__ float bredMax(float v, float* red, int tid) {
    red[tid] = v; __syncthreads();
    for (int s = 128; s > 0; s >>= 1) {
        if (tid < s) red[tid] = fmaxf(red[tid], red[tid + s]);
        __syncthreads();
    }
    float r = red[0]; __syncthreads(); return r;
}
__device__ __forceinline__ float bredSum(float v, float* red, int tid) {
    red[tid] = v; __syncthreads();
    for (int s = 128; s > 0; s >>= 1) {
        if (tid < s) red[tid] += red[tid + s];
        __syncthreads();
    }
    float r = red[0]; __syncthreads(); return r;
}

// 6-tap separable collapsed pyrdown stencil on an LDS plane of size SxS.
__device__ __forceinline__ float stencil6(const float* s, int S, int i, int j) {
    const float w[6] = {1.f, 5.f, 10.f, 10.f, 5.f, 1.f};
    int rx[6];
#pragma unroll
    for (int b = 0; b < 6; ++b) rx[b] = refl(2 * j - 2 + b, S);
    float acc = 0.f;
#pragma unroll
    for (int a = 0; a < 6; ++a) {
        int ry = refl(2 * i - 2 + a, S);
        const float* rp = s + ry * S;
        float r = 0.f;
#pragma unroll
        for (int b = 0; b < 6; ++b) r += w[b] * rp[rx[b]];
        acc += w[a] * r;
    }
    return acc * (1.f / 1024.f);
}

// Tiled separable pyrdown. Block = 32x32 output tile of one plane.
// Stages 68x68 input in LDS (reflect applied at stage time), horizontal
// 6-tap pass -> 68x32, vertical pass -> 32x32 out. If HAS_D: also emits
// d = |in - nearest_up(out)| over the covered 64x64 input region (kept in
// padded LDS) plus min/max of its 16 16x16 stats tiles (tile_kernel fused).
template <int IS, bool HAS_D, int LI>
__global__ __launch_bounds__(256) void pyrdown_tiled(const float* __restrict__ in,
                                                     float* __restrict__ out,
                                                     float* __restrict__ dout,
                                                     float* __restrict__ tileMin,
                                                     float* __restrict__ tileMax) {
    constexpr int SO = IS / 2;
    constexpr int TO = 32;            // output tile edge
    constexpr int TI = 2 * TO + 4;    // 68 staged input edge
    constexpr int TPA = SO / TO;      // output tiles per axis
    __shared__ float sIn[TI * TI];    // 4624
    __shared__ float sH[TI * TO];     // 2176
    __shared__ float sOut[TO * TO];   // 1024
    __shared__ float sD[HAS_D ? 64 * 65 : 1];   // stride 65: bank-conflict-free stats scan
    __shared__ float rmn[HAS_D ? 256 : 1], rmx[HAS_D ? 256 : 1];

    const int tid = threadIdx.x;
    const int p = blockIdx.x / (TPA * TPA);
    const int t = blockIdx.x % (TPA * TPA);
    const int ty = t / TPA, tx = t % TPA;
    const int oy = ty * TO, ox = tx * TO;
    const int iy = 2 * oy - 2, ix = 2 * ox - 2;
    const float* ip = in + (size_t)p * IS * IS;

    for (int k = tid; k < TI * TI; k += 256) {
        int r = k / TI, c = k - r * TI;
        sIn[k] = ip[refl(iy + r, IS) * IS + refl(ix + c, IS)];
    }
    __syncthreads();

    // horizontal: sH[r][j] = sum_b w[b] * sIn[r][2j+b]
    for (int k = tid; k < TI * TO; k += 256) {
        int r = k / TO, j = k - r * TO;
        const float* rp = sIn + r * TI + 2 * j;
        sH[k] = rp[0] + 5.f * rp[1] + 10.f * rp[2] + 10.f * rp[3] + 5.f * rp[4] + rp[5];
    }
    __syncthreads();

    // vertical + out write
    float* op = out + (size_t)p * SO * SO;
    for (int k = tid; k < TO * TO; k += 256) {
        int i = k / TO, j = k - i * TO;
        const float* cp = sH + (2 * i) * TO + j;
        float v = (cp[0] + 5.f * cp[TO] + 10.f * cp[2 * TO] + 10.f * cp[3 * TO] +
                   5.f * cp[4 * TO] + cp[5 * TO]) * (1.f / 1024.f);
        sOut[k] = v;
        op[(size_t)(oy + i) * SO + ox + j] = v;
    }

    if (HAS_D) {
        __syncthreads();
        float* dp = dout + (size_t)p * IS * IS;
        for (int k = tid; k < 4096; k += 256) {
            int yy = k >> 6, xx = k & 63;
            float dv = fabsf(sIn[(yy + 2) * TI + xx + 2] - sOut[(yy >> 1) * TO + (xx >> 1)]);
            sD[yy * 65 + xx] = dv;
            dp[(size_t)(2 * oy + yy) * IS + 2 * ox + xx] = dv;
        }
        __syncthreads();
        // stats: 16 tiles of 16x16; thread tid -> tile s=tid>>4, row r=tid&15
        int s = tid >> 4, r = tid & 15;
        int tr = s >> 2, tc = s & 3;
        const float* rowp = sD + (tr * 16 + r) * 65 + tc * 16;
        float mn = FINF, mx = -FINF;
#pragma unroll
        for (int c = 0; c < 16; ++c) {
            float v = rowp[c];
            mn = fminf(mn, v); mx = fmaxf(mx, v);
        }
        rmn[tid] = mn; rmx[tid] = mx;
        __syncthreads();
        for (int st = 8; st > 0; st >>= 1) {
            if (r < st) {
                rmn[tid] = fminf(rmn[tid], rmn[tid + st]);
                rmx[tid] = fmaxf(rmx[tid], rmx[tid + st]);
            }
            __syncthreads();
        }
        if (r == 0) {
            constexpr int TA = IS / 16;
            constexpr int baseLi = (LI == 0) ? 0 : 6144;
            int gidx = baseLi + p * TA * TA + (ty * 4 + tr) * TA + (tx * 4 + tc);
            tileMin[gidx] = rmn[tid];
            tileMax[gidx] = rmx[tid];
        }
    }
}

// One block per plane: pyr4..pyr8 + d2..d6 entirely in LDS, plus stats (A,B)
// for levels li=2..6.
__global__ __launch_bounds__(256) void fused_small_kernel(const float* __restrict__ pyr3,
                                                          float* __restrict__ dBase,
                                                          float* __restrict__ A,
                                                          float* __restrict__ B) {
    __shared__ float sp3[4096], sd2[4096];
    __shared__ float sp4[1024], sd3[1024];
    __shared__ float sp5[256], sd4[256];
    __shared__ float sp6[64], sd5[64];
    __shared__ float sp7[16], sd6[16];
    __shared__ float red[256];
    __shared__ float tmaxLds[16];
    const int tid = threadIdx.x;
    const int p = blockIdx.x;
    const float* g3 = pyr3 + (size_t)p * 4096;
    for (int k = tid; k < 4096; k += 256) sp3[k] = g3[k];
    __syncthreads();

    // pyr4 (32x32) + d2 (64x64)
    float* d2g = dBase + d_off(2) + (size_t)p * 4096;
    for (int k = tid; k < 1024; k += 256) {
        int i = k >> 5, j = k & 31;
        float v = stencil6(sp3, 64, i, j);
        sp4[k] = v;
#pragma unroll
        for (int di = 0; di < 2; ++di)
#pragma unroll
            for (int dj = 0; dj < 2; ++dj) {
                int y = 2 * i + di, x = 2 * j + dj;
                float dv = fabsf(sp3[y * 64 + x] - v);
                sd2[y * 64 + x] = dv;
                d2g[y * 64 + x] = dv;
            }
    }
    __syncthreads();

    // pyr5 (16x16) + d3 (32x32)
    {
        int i = tid >> 4, j = tid & 15;
        float v = stencil6(sp4, 32, i, j);
        sp5[tid] = v;
        float* d3g = dBase + d_off(3) + (size_t)p * 1024;
#pragma unroll
        for (int di = 0; di < 2; ++di)
#pragma unroll
            for (int dj = 0; dj < 2; ++dj) {
                int y = 2 * i + di, x = 2 * j + dj;
                float dv = fabsf(sp4[y * 32 + x] - v);
                sd3[y * 32 + x] = dv;
                d3g[y * 32 + x] = dv;
            }
    }
    __syncthreads();

    // pyr6 (8x8) + d4 (16x16)
    if (tid < 64) {
        int i = tid >> 3, j = tid & 7;
        float v = stencil6(sp5, 16, i, j);
        sp6[tid] = v;
        float* d4g = dBase + d_off(4) + (size_t)p * 256;
#pragma unroll
        for (int di = 0; di < 2; ++di)
#pragma unroll
            for (int dj = 0; dj < 2; ++dj) {
                int y = 2 * i + di, x = 2 * j + dj;
                float dv = fabsf(sp5[y * 16 + x] - v);
                sd4[y * 16 + x] = dv;
                d4g[y * 16 + x] = dv;
            }
    }
    __syncthreads();

    // pyr7 (4x4) + d5 (8x8)
    if (tid < 16) {
        int i = tid >> 2, j = tid & 3;
        float v = stencil6(sp6, 8, i, j);
        sp7[tid] = v;
        float* d5g = dBase + d_off(5) + (size_t)p * 64;
#pragma unroll
        for (int di = 0; di < 2; ++di)
#pragma unroll
            for (int dj = 0; dj < 2; ++dj) {
                int y = 2 * i + di, x = 2 * j + dj;
                float dv = fabsf(sp6[y * 8 + x] - v);
                sd5[y * 8 + x] = dv;
                d5g[y * 8 + x] = dv;
            }
    }
    __syncthreads();

    // pyr8 (2x2) + d6 (4x4)
    if (tid < 4) {
        int i = tid >> 1, j = tid & 1;
        float v = stencil6(sp7, 4, i, j);
        float* d6g = dBase + d_off(6) + (size_t)p * 16;
#pragma unroll
        for (int di = 0; di < 2; ++di)
#pragma unroll
            for (int dj = 0; dj < 2; ++dj) {
                int y = 2 * i + di, x = 2 * j + dj;
                float dv = fabsf(sp7[y * 4 + x] - v);
                sd6[y * 4 + x] = dv;
                d6g[y * 4 + x] = dv;
            }
    }
    __syncthreads();

    // ---- stats li=2 (S=64, nt=3, ntiles=9) ----
    {
        float mn = FINF, mx = -FINF;
        for (int k = tid; k < 4096; k += 256) {
            float v = sd2[k];
            mn = fminf(mn, v); mx = fmaxf(mx, v);
        }
        mn = bredMin(mn, red, tid);
        mx = bredMax(mx, red, tid);
        {
            int t = tid >> 4, r = tid & 15;
            int ty = t >> 2, tx = t & 3;
            const float* rowp = sd2 + (ty * 16 + r) * 64 + tx * 16;
            float sm = -FINF;
#pragma unroll
            for (int c = 0; c < 16; ++c) sm = fmaxf(sm, rowp[c]);
            red[tid] = sm;
        }
        __syncthreads();
        if (tid < 16) {
            float tm = -FINF;
            for (int r = 0; r < 16; ++r) tm = fmaxf(tm, red[tid * 16 + r]);
            tmaxLds[tid] = tm;
        }
        __syncthreads();
        if (tid == 0) {
            float s = 0.f;
            for (int ty = 0; ty < 3; ++ty)
                for (int tx = 0; tx < 3; ++tx) s += tmaxLds[ty * 4 + tx];
            float inv = 1.f / (mx - mn);
            float lm = (s * (1.f / 9.f) - mn) * inv;
            float g = (1.f - lm) * (1.f - lm);
            A[2 * NPLANES + p] = g * inv;
            B[2 * NPLANES + p] = -mn * g * inv;
        }
        __syncthreads();
    }
    // ---- stats li=3 (S=32, ntiles=1) ----
    {
        float mn = FINF, mx = -FINF;
        for (int k = tid; k < 1024; k += 256) {
            float v = sd3[k];
            mn = fminf(mn, v); mx = fmaxf(mx, v);
        }
        mn = bredMin(mn, red, tid);
        mx = bredMax(mx, red, tid);
        float e = sd3[(tid >> 4) * 32 + (tid & 15)];   // the single interior 16x16 tile
        float tm = bredMax(e, red, tid);
        if (tid == 0) {
            float inv = 1.f / (mx - mn);
            float lm = (tm - mn) * inv;
            float g = (1.f - lm) * (1.f - lm);
            A[3 * NPLANES + p] = g * inv;
            B[3 * NPLANES + p] = -mn * g * inv;
        }
    }
    // ---- stats li=4,5,6 (ntiles=0 -> lm=0) ----
    {
        float v = sd4[tid];
        float mn = bredMin(v, red, tid);
        float mx = bredMax(v, red, tid);
        if (tid == 0) {
            float inv = 1.f / (mx - mn);
            A[4 * NPLANES + p] = inv; B[4 * NPLANES + p] = -mn * inv;
        }
    }
    {
        float v = (tid < 64) ? sd5[tid] : FINF;
        float mn = bredMin(v, red, tid);
        v = (tid < 64) ? sd5[tid] : -FINF;
        float mx = bredMax(v, red, tid);
        if (tid == 0) {
            float inv = 1.f / (mx - mn);
            A[5 * NPLANES + p] = inv; B[5 * NPLANES + p] = -mn * inv;
        }
    }
    {
        float v = (tid < 16) ? sd6[tid] : FINF;
        float mn = bredMin(v, red, tid);
        v = (tid < 16) ? sd6[tid] : -FINF;
        float mx = bredMax(v, red, tid);
        if (tid == 0) {
            float inv = 1.f / (mx - mn);
            A[6 * NPLANES + p] = inv; B[6 * NPLANES + p] = -mn * inv;
        }
    }
}

// One block per (li in {0,1}, plane): fold tile stats -> A,B.
__global__ __launch_bounds__(256) void reduce_kernel(const float* __restrict__ tileMin,
                                                     const float* __restrict__ tileMax,
                                                     float* __restrict__ A,
                                                     float* __restrict__ B) {
    __shared__ float red[256];
    int li = blockIdx.x / NPLANES;
    int p = blockIdx.x % NPLANES;
    int tid = threadIdx.x;
    int TP = (li == 0) ? 256 : 64;     // tiles per plane
    int TA = (li == 0) ? 16 : 8;       // tiles per axis
    int nt = TA - 1;                   // interior tiles per axis
    int base = (li == 0) ? p * 256 : 6144 + p * 64;
    float tmn = (tid < TP) ? tileMin[base + tid] : FINF;
    float tmx = (tid < TP) ? tileMax[base + tid] : -FINF;
    float mn = bredMin(tmn, red, tid);
    float mx = bredMax(tmx, red, tid);
    int ty = (li == 0) ? (tid >> 4) : (tid >> 3);
    int tx = (li == 0) ? (tid & 15) : (tid & 7);
    float s = (tid < TP && ty < nt && tx < nt) ? tmx : 0.f;
    float sum = bredSum(s, red, tid);
    if (tid == 0) {
        float ntiles = (float)(nt * nt);
        float inv = 1.f / (mx - mn);
        float lm = (sum / ntiles - mn) * inv;
        float g = (1.f - lm) * (1.f - lm);
        A[li * NPLANES + p] = g * inv;
        B[li * NPLANES + p] = -mn * g * inv;
    }
}

// Tiled final gather: block = 64x64 output tile of one image b.
// Channel-combined (A pre-multiplied) level patches staged in LDS, then
// each thread bilinearly interpolates a 4x4 register sub-block from LDS.
__global__ __launch_bounds__(256) void final_kernel(const float* __restrict__ dBase,
                                                    const float* __restrict__ A,
                                                    const float* __restrict__ Bc,
                                                    float* __restrict__ out) {
    __shared__ float patch[1650];
    __shared__ float sBtot;
    const int tid = threadIdx.x;
    const int b = blockIdx.x >> 6;
    const int tile = blockIdx.x & 63;
    const int yb = (tile >> 3) << 6;
    const int xb = (tile & 7) << 6;

    if (tid == 0) {
        float s = 0.f;
        for (int k = 0; k < 7; ++k)
            for (int c = 0; c < 3; ++c) s += Bc[k * NPLANES + b * 3 + c];
        sBtot = s;
    }

    const int dims[7] = {34, 18, 10, 6, 4, 3, 3};
    const int lofs[7] = {0, 1156, 1480, 1580, 1616, 1632, 1641};
    int baseY[7], baseX[7];
#pragma unroll
    for (int li = 0; li < 7; ++li) {
        const int S = 256 >> li;
        const float s = 1.f / (float)(2 << li);
        baseY[li] = (int)floorf((yb + 0.5f) * s - 0.5f);
        baseX[li] = (int)floorf((xb + 0.5f) * s - 0.5f);
        const int dim = dims[li];
        const int n = dim * dim;
        const float* d0p = dBase + d_off(li) + (size_t)(b * 3) * S * S;
        const float* d1p = d0p + S * S;
        const float* d2p = d1p + S * S;
        const float A0 = A[li * NPLANES + b * 3 + 0];
        const float A1 = A[li * NPLANES + b * 3 + 1];
        const float A2 = A[li * NPLANES + b * 3 + 2];
        for (int k = tid; k < n; k += 256) {
            int r = k / dim, c = k - r * dim;
            int sr = min(max(baseY[li] + r, 0), S - 1);
            int sc = min(max(baseX[li] + c, 0), S - 1);
            int si = sr * S + sc;
            patch[lofs[li] + k] = A0 * d0p[si] + A1 * d1p[si] + A2 * d2p[si];
        }
    }
    __syncthreads();

    const int ty = tid >> 4, tx = tid & 15;
    const int gy0 = yb + (ty << 2), gx0 = xb + (tx << 2);
    float acc[4][4];
#pragma unroll
    for (int i = 0; i < 4; ++i)
#pragma unroll
        for (int j = 0; j < 4; ++j) acc[i][j] = 0.f;

#pragma unroll
    for (int li = 0; li < 7; ++li) {
        const int dim = dims[li];
        const float* P = patch + lofs[li];
        const float s = 1.f / (float)(2 << li);
        int pr[4], pc[4];
        float wy[4], wx[4];
#pragma unroll
        for (int k = 0; k < 4; ++k) {
            float fy = (gy0 + k + 0.5f) * s - 0.5f;
            float fl = floorf(fy);
            wy[k] = fy - fl;
            pr[k] = (int)fl - baseY[li];
            float fx = (gx0 + k + 0.5f) * s - 0.5f;
            fl = floorf(fx);
            wx[k] = fx - fl;
            pc[k] = (int)fl - baseX[li];
        }
#pragma unroll
        for (int i = 0; i < 4; ++i) {
            const float* r0 = P + pr[i] * dim;
            const float* r1 = r0 + dim;
#pragma unroll
            for (int j = 0; j < 4; ++j) {
                float a0 = r0[pc[j]], a1 = r0[pc[j] + 1];
                float b0 = r1[pc[j]], b1 = r1[pc[j] + 1];
                float h0 = a0 + wx[j] * (a1 - a0);
                float h1 = b0 + wx[j] * (b1 - b0);
                acc[i][j] += h0 + wy[i] * (h1 - h0);
            }
        }
    }

    const float bt = sBtot;
    float* op = out + ((size_t)b * 512 + gy0) * 512 + gx0;
#pragma unroll
    for (int i = 0; i < 4; ++i) {
        float4 v;
        v.x = (acc[i][0] + bt) * (1.f / 3.f);
        v.y = (acc[i][1] + bt) * (1.f / 3.f);
        v.z = (acc[i][2] + bt) * (1.f / 3.f);
        v.w = (acc[i][3] + bt) * (1.f / 3.f);
        *(float4*)(op + (size_t)i * 512) = v;
    }
}

extern "C" void kernel_launch(void* const* d_in, const int* in_sizes, int n_in,
                              void* d_out, int out_size, void* d_ws, size_t ws_size,
                              hipStream_t stream) {
    (void)in_sizes; (void)n_in; (void)out_size; (void)ws_size;
    const float* x = (const float*)d_in[0];
    float* ws = (float*)d_ws;
    float* out = (float*)d_out;

    // Workspace layout (float offsets):
    float* pyr1 = ws;                  // 256^2*24 = 1572864
    float* pyr2 = ws + 1572864;        // 128^2*24 =  393216
    float* pyr3 = ws + 1966080;        //  64^2*24 =   98304
    float* dBase = ws + 2064384;       // d0..d6   = 2097024
    float* tileMin = ws + 4161408;     // 7680
    float* tileMax = ws + 4169088;     // 7680
    float* A = ws + 4176768;           // 168
    float* Bc = ws + 4176936;          // 168

    // Level 1 from raw x (initial _norm_pc is an affine no-op for the output)
    pyrdown_tiled<512, false, 0><<<NPLANES * 64, 256, 0, stream>>>(x, pyr1, nullptr, nullptr, nullptr);
    pyrdown_tiled<256, true, 0><<<NPLANES * 16, 256, 0, stream>>>(pyr1, pyr2, dBase + d_off(0), tileMin, tileMax);
    pyrdown_tiled<128, true, 1><<<NPLANES * 4, 256, 0, stream>>>(pyr2, pyr3, dBase + d_off(1), tileMin, tileMax);
    fused_small_kernel<<<NPLANES, 256, 0, stream>>>(pyr3, dBase, A, Bc);
    reduce_kernel<<<2 * NPLANES, 256, 0, stream>>>(tileMin, tileMax, A, Bc);
    final_kernel<<<8 * 64, 256, 0, stream>>>(dBase, A, Bc, out);
}